// Round 9
// baseline (56.446 us; speedup 1.0000x reference)
//
#include <hip/hip_runtime.h>
#include <math.h>

constexpr int IMG_H = 1024;
constexpr int IMG_W = 2048;
constexpr int BLOCK = 256;
constexpr int GRID_MAIN = 1024;   // ~3.8 iters/thread -> pipeline has body
constexpr int GRID_FB   = 2048;

constexpr size_t PARTIALS_BYTES = 64 * 1024;
constexpr size_t TEX16_BYTES = (size_t)IMG_H * IMG_W * 2;  // u16 R5G5B5W1 = 4 MB (L2-resident)

constexpr float QSCALE = 262144.0f;       // 2^18 fixed-point loss scale
constexpr double QINV  = 1.0 / 262144.0;

typedef float f32x4  __attribute__((ext_vector_type(4)));
typedef float f32x4a __attribute__((ext_vector_type(4), aligned(8)));
typedef float f32x2a __attribute__((ext_vector_type(2), aligned(8)));

#define PI_F 3.14159265358979323846f

__device__ __forceinline__ unsigned short pack5551(float r, float g, float b, float w) {
    const unsigned ur = (unsigned)(r * 31.0f + 0.5f);
    const unsigned ug = (unsigned)(g * 31.0f + 0.5f);
    const unsigned ub = (unsigned)(b * 31.0f + 0.5f);
    const unsigned uw = (w >= 0.5f) ? 1u : 0u;
    return (unsigned short)(ur | (ug << 5) | (ub << 10) | (uw << 15));
}

// atan(a)/(2pi), a in [0,1]; odd minimax deg-11, coeffs pre-divided by 2pi
__device__ __forceinline__ float atan_turns_poly(float a) {
    const float s = a * a;
    float p = -0.001865487f;
    p = p * s + 0.008380035f;
    p = p * s - 0.018530866f;
    p = p * s + 0.030803399f;
    p = p * s - 0.05293865f;
    p = p * s + 0.15915132f;
    return p * a;
}

__device__ __forceinline__ float atan2_turns(float y, float x) {
    const float ax = fabsf(x), ay = fabsf(y);
    const float mx = fmaxf(ax, ay), mn = fminf(ax, ay);
    const float a = mn * __builtin_amdgcn_rcpf(mx);
    float r = atan_turns_poly(a);
    r = (ay > ax) ? (0.25f - r) : r;
    r = (x < 0.0f) ? (0.5f - r) : r;
    return (y < 0.0f) ? -r : r;
}

// ---------------- pack: (img f32x3, imgw f32x1) -> u16 R5G5B5W1 ----------------
__global__ __launch_bounds__(BLOCK) void pack_tex16(
    const f32x4* __restrict__ img4,
    const f32x4* __restrict__ imgw4,
    ushort4* __restrict__ tex)
{
    const int g = blockIdx.x * BLOCK + threadIdx.x;
    if (g >= IMG_H * IMG_W / 4) return;
    const f32x4 a = img4[3 * g + 0];
    const f32x4 b = img4[3 * g + 1];
    const f32x4 c = img4[3 * g + 2];
    const f32x4 w = imgw4[g];

    ushort4 t;
    t.x = pack5551(a.x, a.y, a.z, w.x);
    t.y = pack5551(a.w, b.x, b.y, w.y);
    t.z = pack5551(b.z, b.w, c.x, w.z);
    t.w = pack5551(c.y, c.z, c.w, w.w);
    tex[g] = t;
}

struct G2 {
    float X0, Y0, Z0, X1, Y1, Z1;
    float CR0, CG0, CB0, CR1, CG1, CB1, PW0, PW1;
    bool has2, valid;
};

// ---------------- stage 1: pipelined 2 pts/thread, fixed-point accum ----------------
__global__ __launch_bounds__(BLOCK, 4) void sampling_loss_tex16p(
    const float* __restrict__ translation,
    const float* __restrict__ yaw,
    const float* __restrict__ pitch,
    const float* __restrict__ roll,
    const float* __restrict__ xyz,
    const float* __restrict__ rgb,
    const unsigned short* __restrict__ tex,
    const float* __restrict__ pcdw,
    double* __restrict__ partials,
    int N)
{
    const float cyw = cosf(yaw[0]),   syw = sinf(yaw[0]);
    const float cpw = cosf(pitch[0]), spw = sinf(pitch[0]);
    const float crw = cosf(roll[0]),  srw = sinf(roll[0]);

    const float R00 = cyw * cpw;
    const float R01 = -syw * crw + cyw * spw * srw;
    const float R02 =  syw * srw + cyw * spw * crw;
    const float R10 =  syw * cpw;
    const float R11 =  cyw * crw + syw * spw * srw;
    const float R12 = -cyw * srw + syw * spw * crw;
    const float R20 = -spw;
    const float R21 =  cpw * srw;
    const float R22 =  cpw * crw;

    const float tx = translation[0], ty = translation[1], tz = translation[2];
    const float inv31 = 1.0f / 31.0f;

    const int nGroups = (N + 1) >> 1;
    const int stride = gridDim.x * BLOCK;

    long long accL = 0;
    int accM = 0;

    auto load_group = [&](int g) -> G2 {
        G2 r;
        r.valid = (g < nGroups);
        if (!r.valid) {
            r.X0 = r.Y0 = r.Z0 = r.X1 = r.Y1 = r.Z1 = 0.0f;
            r.CR0 = r.CG0 = r.CB0 = r.CR1 = r.CG1 = r.CB1 = 0.0f;
            r.PW0 = r.PW1 = 0.0f; r.has2 = false;
            return r;
        }
        const int i0 = 2 * g;
        r.has2 = (i0 + 1 < N);
        if (r.has2) {
            const f32x4a v0 = __builtin_nontemporal_load((const f32x4a*)&xyz[6 * g]);
            const f32x2a v1 = __builtin_nontemporal_load((const f32x2a*)&xyz[6 * g + 4]);
            const f32x4a c0 = __builtin_nontemporal_load((const f32x4a*)&rgb[6 * g]);
            const f32x2a c1 = __builtin_nontemporal_load((const f32x2a*)&rgb[6 * g + 4]);
            const f32x2a pw = __builtin_nontemporal_load((const f32x2a*)&pcdw[2 * g]);
            r.X0 = v0.x; r.Y0 = v0.y; r.Z0 = v0.z;
            r.X1 = v0.w; r.Y1 = v1.x; r.Z1 = v1.y;
            r.CR0 = c0.x; r.CG0 = c0.y; r.CB0 = c0.z;
            r.CR1 = c0.w; r.CG1 = c1.x; r.CB1 = c1.y;
            r.PW0 = pw.x; r.PW1 = pw.y;
        } else {
            r.X0 = xyz[3 * i0]; r.Y0 = xyz[3 * i0 + 1]; r.Z0 = xyz[3 * i0 + 2];
            r.CR0 = rgb[3 * i0]; r.CG0 = rgb[3 * i0 + 1]; r.CB0 = rgb[3 * i0 + 2];
            r.PW0 = pcdw[i0];
            r.X1 = r.X0; r.Y1 = r.Y0; r.Z1 = r.Z0;
            r.CR1 = r.CR0; r.CG1 = r.CG0; r.CB1 = r.CB0; r.PW1 = 0.0f;
        }
        return r;
    };

    auto project = [&](float X, float Y, float Z,
                       int& i00, int& i01, int& i10, int& i11,
                       float& w00, float& w01, float& w10, float& w11) {
        const float px = X - tx, py = Y - ty, pz = Z - tz;
        const float nx = R00 * px + R01 * py + R02 * pz;
        const float ny = R10 * px + R11 * py + R12 * pz;
        const float nz = R20 * px + R21 * py + R22 * pz;

        const float t_phi = atan2_turns(ny, nx);
        const float rxy   = sqrtf(nx * nx + ny * ny);
        const float t_th  = atan2_turns(rxy, nz);

        float fx = (0.5f - t_phi) * (float)IMG_W - 0.5f;
        float fy = t_th * (2.0f * (float)IMG_H) - 0.5f;
        fx = fminf(fmaxf(fx, 0.0f), (float)(IMG_W - 1));
        fy = fminf(fmaxf(fy, 0.0f), (float)(IMG_H - 1));

        const float x0f = floorf(fx), y0f = floorf(fy);
        const float wx = fx - x0f,    wy = fy - y0f;
        const int x0 = (int)x0f, y0 = (int)y0f;
        const int x1 = min(x0 + 1, IMG_W - 1);
        const int y1 = min(y0 + 1, IMG_H - 1);

        i00 = y0 * IMG_W + x0;  i01 = y0 * IMG_W + x1;
        i10 = y1 * IMG_W + x0;  i11 = y1 * IMG_W + x1;
        w00 = (1.0f - wx) * (1.0f - wy);
        w01 = wx * (1.0f - wy);
        w10 = (1.0f - wx) * wy;
        w11 = wx * wy;
    };

    int g = blockIdx.x * BLOCK + threadIdx.x;
    G2 cur = load_group(g);

    while (g < nGroups) {
        const int gn = g + stride;
        G2 nxt = load_group(gn);   // prefetch: issued before current group's compute/gather

        // project both points (independent VALU chains)
        int a00, a01, a10, a11, b00, b01, b10, b11;
        float wa00, wa01, wa10, wa11, wb00, wb01, wb10, wb11;
        project(cur.X0, cur.Y0, cur.Z0, a00, a01, a10, a11, wa00, wa01, wa10, wa11);
        project(cur.X1, cur.Y1, cur.Z1, b00, b01, b10, b11, wb00, wb01, wb10, wb11);

        // 8 gathers back-to-back
        const unsigned tA00 = tex[a00];
        const unsigned tA01 = tex[a01];
        const unsigned tA10 = tex[a10];
        const unsigned tA11 = tex[a11];
        const unsigned tB00 = tex[b00];
        const unsigned tB01 = tex[b01];
        const unsigned tB10 = tex[b10];
        const unsigned tB11 = tex[b11];

        float lsum = 0.0f;
        int   msum = 0;
        {
            const float r5 = wa00 * (float)(tA00 & 31u)         + wa01 * (float)(tA01 & 31u)
                           + wa10 * (float)(tA10 & 31u)         + wa11 * (float)(tA11 & 31u);
            const float g5 = wa00 * (float)((tA00 >> 5) & 31u)  + wa01 * (float)((tA01 >> 5) & 31u)
                           + wa10 * (float)((tA10 >> 5) & 31u)  + wa11 * (float)((tA11 >> 5) & 31u);
            const float b5 = wa00 * (float)((tA00 >> 10) & 31u) + wa01 * (float)((tA01 >> 10) & 31u)
                           + wa10 * (float)((tA10 >> 10) & 31u) + wa11 * (float)((tA11 >> 10) & 31u);
            const float w1 = wa00 * (float)(tA00 >> 15)         + wa01 * (float)(tA01 >> 15)
                           + wa10 * (float)(tA10 >> 15)         + wa11 * (float)(tA11 >> 15);
            const float dr = r5 * inv31 - cur.CR0;
            const float dg = g5 * inv31 - cur.CG0;
            const float db = b5 * inv31 - cur.CB0;
            const float raw = sqrtf(dr * dr + dg * dg + db * db);
            const bool mask = !((r5 == 0.0f) && (g5 == 0.0f) && (b5 == 0.0f));
            if (mask) { lsum += 0.5f * (w1 + cur.PW0) * raw; msum += 1; }
        }
        {
            const float r5 = wb00 * (float)(tB00 & 31u)         + wb01 * (float)(tB01 & 31u)
                           + wb10 * (float)(tB10 & 31u)         + wb11 * (float)(tB11 & 31u);
            const float g5 = wb00 * (float)((tB00 >> 5) & 31u)  + wb01 * (float)((tB01 >> 5) & 31u)
                           + wb10 * (float)((tB10 >> 5) & 31u)  + wb11 * (float)((tB11 >> 5) & 31u);
            const float b5 = wb00 * (float)((tB00 >> 10) & 31u) + wb01 * (float)((tB01 >> 10) & 31u)
                           + wb10 * (float)((tB10 >> 10) & 31u) + wb11 * (float)((tB11 >> 10) & 31u);
            const float w1 = wb00 * (float)(tB00 >> 15)         + wb01 * (float)(tB01 >> 15)
                           + wb10 * (float)(tB10 >> 15)         + wb11 * (float)(tB11 >> 15);
            const float dr = r5 * inv31 - cur.CR1;
            const float dg = g5 * inv31 - cur.CG1;
            const float db = b5 * inv31 - cur.CB1;
            const float raw = sqrtf(dr * dr + dg * dg + db * db);
            const bool mask = (!((r5 == 0.0f) && (g5 == 0.0f) && (b5 == 0.0f))) && cur.has2;
            if (mask) { lsum += 0.5f * (w1 + cur.PW1) * raw; msum += 1; }
        }

        // fixed-point accumulation: integer adds, no f64 in the hot loop
        accL += (long long)__float2int_rn(lsum * QSCALE);
        accM += msum;

        g = gn;
        cur = nxt;
    }

    // deterministic block reduction (integer)
    for (int off = 32; off > 0; off >>= 1) {
        accL += __shfl_down(accL, off);
        accM += __shfl_down(accM, off);
    }
    __shared__ long long sL[BLOCK / 64];
    __shared__ int       sM[BLOCK / 64];
    const int lane = threadIdx.x & 63;
    const int wave = threadIdx.x >> 6;
    if (lane == 0) { sL[wave] = accL; sM[wave] = accM; }
    __syncthreads();
    if (threadIdx.x == 0) {
        long long L = 0; long long M = 0;
        for (int w = 0; w < BLOCK / 64; ++w) { L += sL[w]; M += (long long)sM[w]; }
        partials[2 * blockIdx.x + 0] = (double)L * QINV;
        partials[2 * blockIdx.x + 1] = (double)M;
    }
}

// ---------------- fallback stage 1 (no scratch texture) ----------------
__global__ __launch_bounds__(BLOCK) void sampling_loss_partial(
    const float* __restrict__ translation,
    const float* __restrict__ yaw,
    const float* __restrict__ pitch,
    const float* __restrict__ roll,
    const float* __restrict__ xyz,
    const float* __restrict__ rgb,
    const float* __restrict__ img,
    const float* __restrict__ imgw,
    const float* __restrict__ pcdw,
    double* __restrict__ partials,
    int N)
{
    const float cyw = cosf(yaw[0]),   syw = sinf(yaw[0]);
    const float cpw = cosf(pitch[0]), spw = sinf(pitch[0]);
    const float crw = cosf(roll[0]),  srw = sinf(roll[0]);
    const float R00 = cyw * cpw;
    const float R01 = -syw * crw + cyw * spw * srw;
    const float R02 =  syw * srw + cyw * spw * crw;
    const float R10 =  syw * cpw;
    const float R11 =  cyw * crw + syw * spw * srw;
    const float R12 = -cyw * srw + syw * spw * crw;
    const float R20 = -spw;
    const float R21 =  cpw * srw;
    const float R22 =  cpw * crw;
    const float tx = translation[0], ty = translation[1], tz = translation[2];

    double acc_loss = 0.0, acc_mask = 0.0;
    for (int i = blockIdx.x * BLOCK + threadIdx.x; i < N; i += gridDim.x * BLOCK) {
        const float px = xyz[3 * i + 0] - tx;
        const float py = xyz[3 * i + 1] - ty;
        const float pz = xyz[3 * i + 2] - tz;
        const float nx = R00 * px + R01 * py + R02 * pz;
        const float ny = R10 * px + R11 * py + R12 * pz;
        const float nz = R20 * px + R21 * py + R22 * pz;
        const float phi   = atan2f(ny, nx) + PI_F;
        const float theta = atan2f(sqrtf(nx * nx + ny * ny), nz);
        const float cx = 2.0f * (1.0f - phi / (2.0f * PI_F)) - 1.0f;
        const float cyv = 2.0f * (theta / PI_F) - 1.0f;
        float fx = (cx + 1.0f) * 0.5f * (float)IMG_W - 0.5f;
        float fy = (cyv + 1.0f) * 0.5f * (float)IMG_H - 0.5f;
        fx = fminf(fmaxf(fx, 0.0f), (float)(IMG_W - 1));
        fy = fminf(fmaxf(fy, 0.0f), (float)(IMG_H - 1));
        const float x0f = floorf(fx), y0f = floorf(fy);
        const float wx = fx - x0f,    wy = fy - y0f;
        const int x0 = (int)x0f, y0 = (int)y0f;
        const int x1 = min(x0 + 1, IMG_W - 1);
        const int y1 = min(y0 + 1, IMG_H - 1);
        const float w00 = (1.0f - wx) * (1.0f - wy);
        const float w01 = wx * (1.0f - wy);
        const float w10 = (1.0f - wx) * wy;
        const float w11 = wx * wy;
        const float* p00 = img + (size_t)(y0 * IMG_W + x0) * 3;
        const float* p01 = img + (size_t)(y0 * IMG_W + x1) * 3;
        const float* p10 = img + (size_t)(y1 * IMG_W + x0) * 3;
        const float* p11 = img + (size_t)(y1 * IMG_W + x1) * 3;
        const float s0 = w00 * p00[0] + w01 * p01[0] + w10 * p10[0] + w11 * p11[0];
        const float s1 = w00 * p00[1] + w01 * p01[1] + w10 * p10[1] + w11 * p11[1];
        const float s2 = w00 * p00[2] + w01 * p01[2] + w10 * p10[2] + w11 * p11[2];
        const float wimg = w00 * imgw[y0 * IMG_W + x0] + w01 * imgw[y0 * IMG_W + x1]
                         + w10 * imgw[y1 * IMG_W + x0] + w11 * imgw[y1 * IMG_W + x1];
        const float dr = s0 - rgb[3 * i + 0];
        const float dg = s1 - rgb[3 * i + 1];
        const float db = s2 - rgb[3 * i + 2];
        const float raw = sqrtf(dr * dr + dg * dg + db * db);
        const bool mask = !((s0 == 0.0f) && (s1 == 0.0f) && (s2 == 0.0f));
        const float li = 0.5f * (wimg + pcdw[i]) * raw;
        if (mask) { acc_loss += (double)li; acc_mask += 1.0; }
    }
    for (int off = 32; off > 0; off >>= 1) {
        acc_loss += __shfl_down(acc_loss, off);
        acc_mask += __shfl_down(acc_mask, off);
    }
    __shared__ double sL[BLOCK / 64];
    __shared__ double sM[BLOCK / 64];
    const int lane = threadIdx.x & 63;
    const int wave = threadIdx.x >> 6;
    if (lane == 0) { sL[wave] = acc_loss; sM[wave] = acc_mask; }
    __syncthreads();
    if (threadIdx.x == 0) {
        double L = 0.0, M = 0.0;
        for (int w = 0; w < BLOCK / 64; ++w) { L += sL[w]; M += sM[w]; }
        partials[2 * blockIdx.x + 0] = L;
        partials[2 * blockIdx.x + 1] = M;
    }
}

// ---------------- stage 2: deterministic finalize ----------------
__global__ __launch_bounds__(BLOCK) void sampling_loss_finalize(
    const double* __restrict__ partials, float* __restrict__ out, int nBlocks)
{
    double L = 0.0, M = 0.0;
    for (int i = threadIdx.x; i < nBlocks; i += BLOCK) {
        L += partials[2 * i + 0];
        M += partials[2 * i + 1];
    }
    for (int off = 32; off > 0; off >>= 1) {
        L += __shfl_down(L, off);
        M += __shfl_down(M, off);
    }
    __shared__ double sL[BLOCK / 64];
    __shared__ double sM[BLOCK / 64];
    const int lane = threadIdx.x & 63;
    const int wave = threadIdx.x >> 6;
    if (lane == 0) { sL[wave] = L; sM[wave] = M; }
    __syncthreads();
    if (threadIdx.x == 0) {
        double tl = 0.0, tm = 0.0;
        for (int w = 0; w < BLOCK / 64; ++w) { tl += sL[w]; tm += sM[w]; }
        out[0] = (float)(tl / tm);
    }
}

extern "C" void kernel_launch(void* const* d_in, const int* in_sizes, int n_in,
                              void* d_out, int out_size, void* d_ws, size_t ws_size,
                              hipStream_t stream) {
    const float* translation = (const float*)d_in[0];
    const float* yaw         = (const float*)d_in[1];
    const float* pitch       = (const float*)d_in[2];
    const float* roll        = (const float*)d_in[3];
    const float* xyz         = (const float*)d_in[4];
    const float* rgb         = (const float*)d_in[5];
    const float* img         = (const float*)d_in[6];
    const float* imgw        = (const float*)d_in[7];
    const float* pcdw        = (const float*)d_in[8];

    const int N = in_sizes[8];

    double* partials = (double*)d_ws;
    float* out = (float*)d_out;

    if (ws_size >= PARTIALS_BYTES + TEX16_BYTES) {
        unsigned short* tex = (unsigned short*)((char*)d_ws + PARTIALS_BYTES);
        const int packThreads = IMG_H * IMG_W / 4;
        pack_tex16<<<(packThreads + BLOCK - 1) / BLOCK, BLOCK, 0, stream>>>(
            (const f32x4*)img, (const f32x4*)imgw, (ushort4*)tex);

        sampling_loss_tex16p<<<GRID_MAIN, BLOCK, 0, stream>>>(
            translation, yaw, pitch, roll, xyz, rgb, tex, pcdw, partials, N);
        sampling_loss_finalize<<<1, BLOCK, 0, stream>>>(partials, out, GRID_MAIN);
    } else {
        sampling_loss_partial<<<GRID_FB, BLOCK, 0, stream>>>(
            translation, yaw, pitch, roll, xyz, rgb, img, imgw, pcdw, partials, N);
        sampling_loss_finalize<<<1, BLOCK, 0, stream>>>(partials, out, GRID_FB);
    }
}